// Round 6
// baseline (197.530 us; speedup 1.0000x reference)
//
#include <hip/hip_runtime.h>

#define DEV __device__ __forceinline__

typedef unsigned short u16;
typedef __bf16 bf16x8 __attribute__((ext_vector_type(8)));
typedef u16 u16x4 __attribute__((ext_vector_type(4)));
typedef float fx4 __attribute__((ext_vector_type(4)));

#define NPIX 65536
#define OFF_WCAT  16777216
#define OFF_WOUT  16908288
#define OFF_Q     16941056
#define OFF_BIAS  67272704
#define OFF_GATE  68321280
#define TEN_ELEMS 8388608  // u16 elements per Q/K/V tensor

DEV u16 f2bf(float f){
  unsigned u = __builtin_bit_cast(unsigned, f);
  u += 0x7fffu + ((u>>16)&1u);
  return (u16)(u>>16);
}
DEV float bf2f(u16 s){ return __builtin_bit_cast(float, ((unsigned)s)<<16); }

typedef __attribute__((address_space(1))) unsigned gas_t;
typedef __attribute__((address_space(3))) unsigned las_t;
DEV void gl16(const void* g, void* l){
  __builtin_amdgcn_global_load_lds((gas_t*)g, (las_t*)l, 16, 0, 0);
}

// XOR-ish swizzle for [row][32] bf16 LDS tiles (row stride 64B): chunk' = (cc + row/2) & 3
DEV int swz(int row, int cc){ return row*32 + (((cc + (row>>1))&3)<<3); }

// Stage one 128x32 A-tile + 128x32 B-tile into LDS (4 gl16 per thread).
// Source address pre-swizzled so linear LDS + swizzled read works.
DEV void stage2(const u16* __restrict__ ga, const u16* __restrict__ gb,
                u16* lA, u16* lB, int t, int w){
  #pragma unroll
  for (int s=0; s<2; ++s){
    int idx = (s<<8) + t;
    int row = idx>>2, ccL = idx&3;
    int ccG = (ccL - (row>>1)) & 3;
    gl16(ga + (size_t)row*128 + (ccG<<3), lA + (((s<<2)+w)<<9));
    gl16(gb + (size_t)row*128 + (ccG<<3), lB + (((s<<2)+w)<<9));
  }
}

// One K=32 MFMA step from staged LDS tiles.
DEV void mfma16(const u16* lA, const u16* lB, fx4 (&acc)[4][4],
                int wm, int wn, int cbase, int g){
  bf16x8 a[4], b[4];
  #pragma unroll
  for (int mi=0; mi<4; ++mi)
    a[mi] = *(const bf16x8*)(lA + swz((wm<<6)+(mi<<4)+cbase, g));
  #pragma unroll
  for (int ni=0; ni<4; ++ni)
    b[ni] = *(const bf16x8*)(lB + swz((wn<<6)+(ni<<4)+cbase, g));
  #pragma unroll
  for (int mi=0; mi<4; ++mi)
    #pragma unroll
    for (int ni=0; ni<4; ++ni)
      acc[mi][ni] = __builtin_amdgcn_mfma_f32_16x16x32_bf16(a[mi], b[ni], acc[mi][ni], 0,0,0);
}

#define SBAR   __builtin_amdgcn_s_barrier()
#define SCHEDB __builtin_amdgcn_sched_barrier(0)

// ---------------- K0: weight convert/transpose (column-permuted) ----------------
__global__ __launch_bounds__(256) void k_prep(const float* __restrict__ Wqkv,
                                              const float* __restrict__ Wgate,
                                              const float* __restrict__ Wout,
                                              u16* __restrict__ wcat, u16* __restrict__ woutT){
  int idx = blockIdx.x*256 + threadIdx.x;   // grid = 256 blocks -> idx < 65536
  int np = idx>>7, k = idx&127;
  int tt = np>>7, hh = (np>>5)&3, c = np&31;
  float v;
  if (tt < 3) v = Wqkv[k*384 + c*12 + tt*4 + hh];
  else        v = Wgate[k*128 + c*4 + hh];
  wcat[idx] = f2bf(v);
  if (idx < 16384){
    int n = idx>>7, kp = idx&127;
    int h2 = kp>>5, c2 = kp&31;
    woutT[idx] = f2bf(Wout[(c2*4 + h2)*128 + n]);
  }
}

// ---------------- K1: LN + bias projection ----------------
__global__ __launch_bounds__(256) void k_ln(const float* __restrict__ x,
                                            const float* __restrict__ lng,
                                            const float* __restrict__ lnb,
                                            const float* __restrict__ Wb,
                                            u16* __restrict__ lnx, float* __restrict__ bias_s){
  int lane = threadIdx.x & 63;
  int wid  = (blockIdx.x*256 + threadIdx.x)>>6;
  int nw   = (gridDim.x*256)>>6;
  int c0 = lane<<1;
  float g0 = lng[c0], g1 = lng[c0+1], be0 = lnb[c0], be1 = lnb[c0+1];
  float4 wb0 = *(const float4*)(Wb + (c0<<2));
  float4 wb1 = *(const float4*)(Wb + (c0<<2) + 4);
  for (int p = wid; p < NPIX; p += nw){
    float2 xv = *(const float2*)(x + (((size_t)p)<<7) + c0);
    float s = xv.x + xv.y;
    float s2 = xv.x*xv.x + xv.y*xv.y;
    #pragma unroll
    for (int msk=32; msk>=1; msk>>=1){ s += __shfl_xor(s,msk); s2 += __shfl_xor(s2,msk); }
    float mu = s*(1.f/128.f);
    float var = s2*(1.f/128.f) - mu*mu;
    float rs = rsqrtf(var + 1e-5f);
    float y0 = (xv.x-mu)*rs*g0 + be0;
    float y1 = (xv.y-mu)*rs*g1 + be1;
    unsigned pk = (unsigned)f2bf(y0) | (((unsigned)f2bf(y1))<<16);
    *(unsigned*)(lnx + (((size_t)p)<<7) + c0) = pk;
    float d0 = y0*wb0.x + y1*wb1.x;
    float d1 = y0*wb0.y + y1*wb1.y;
    float d2 = y0*wb0.z + y1*wb1.z;
    float d3 = y0*wb0.w + y1*wb1.w;
    #pragma unroll
    for (int msk=32; msk>=1; msk>>=1){
      d0 += __shfl_xor(d0,msk); d1 += __shfl_xor(d1,msk);
      d2 += __shfl_xor(d2,msk); d3 += __shfl_xor(d3,msk);
    }
    if (lane==0){
      int pi = p>>8, pj = p&255;
      int o = (pj<<8) + pi;          // bias_s[h][j=pj][k=pi]
      bias_s[o] = d0;
      bias_s[65536 + o] = d1;
      bias_s[131072 + o] = d2;
      bias_s[196608 + o] = d3;
    }
  }
}

// ---------------- K2: qkv+gate projection GEMM (prefetch-all, counted vmcnt) ----------------
// Output layouts: Q,K: [i][h][j][c]; V: [i][h][c][j] (transposed); gate: [pix][h*32+c]
// Grid: 2048 linear blocks, XCD-chunked swizzle: each XCD owns 64 m-tiles x all 4 n.
__global__ __launch_bounds__(256) void k_qkv(const u16* __restrict__ lnx,
                                             const u16* __restrict__ wcat,
                                             const float* __restrict__ b_gate,
                                             u16* __restrict__ qkv, u16* __restrict__ gateb){
  __shared__ __align__(16) u16 smem[32768];   // A0..A3 | B0..B3 (8x8KB); Ep aliases after
  int t = threadIdx.x, l = t&63, w = t>>6;
  int phys = blockIdx.x;
  int virt = ((phys&7)<<8) + (phys>>3);       // XCD-chunked bijection (2048 % 8 == 0)
  int m0 = (virt>>2)<<7, n0 = (virt&3)<<7;
  int tt2 = virt&3;
  int wm = w>>1, wn = w&1;
  int rbase = (l>>4)<<2, cbase = l&15, g = l>>4;
  const u16* gA = lnx  + (size_t)m0*128;
  const u16* gB = wcat + (size_t)n0*128;
  // issue ALL staging loads (16 per thread, in-order completion => counted gating)
  #pragma unroll
  for (int c=0; c<4; ++c)
    stage2(gA + (c<<5), gB + (c<<5), smem + (c<<12), smem + 16384 + (c<<12), t, w);
  fx4 acc[4][4] = {};
  asm volatile("s_waitcnt vmcnt(12)" ::: "memory"); SBAR; SCHEDB;
  mfma16(smem,        smem+16384, acc, wm, wn, cbase, g);
  asm volatile("s_waitcnt vmcnt(8)" ::: "memory");  SBAR; SCHEDB;
  mfma16(smem+4096,   smem+20480, acc, wm, wn, cbase, g);
  asm volatile("s_waitcnt vmcnt(4)" ::: "memory");  SBAR; SCHEDB;
  mfma16(smem+8192,   smem+24576, acc, wm, wn, cbase, g);
  asm volatile("s_waitcnt vmcnt(0)" ::: "memory");  SBAR; SCHEDB;
  mfma16(smem+12288,  smem+28672, acc, wm, wn, cbase, g);
  // Epilogue: restage 128x128 tile through LDS (aliased on smem) in two 64-row halves.
  u16* Ep = smem;
  for (int half=0; half<2; ++half){
    __syncthreads();
    if (wm == half){
      #pragma unroll
      for (int mi=0; mi<4; ++mi)
        #pragma unroll
        for (int ni=0; ni<4; ++ni){
          int coln = (wn<<6) + (ni<<4) + cbase;
          if (tt2 == 2){
            // V^T restage: EpT[coln][row], pack 4 rows per b64
            u16x4 w4;
            #pragma unroll
            for (int r=0; r<4; ++r) w4[r] = f2bf(acc[mi][ni][r]);
            *(u16x4*)(Ep + coln*72 + (mi<<4) + rbase) = w4;
          } else if (tt2 == 3){
            float bg = b_gate[((coln&31)<<2) + (coln>>5)];
            #pragma unroll
            for (int r=0; r<4; ++r){
              int row = (mi<<4) + rbase + r;
              float v = acc[mi][ni][r] + bg;
              Ep[row*132 + coln] = f2bf(1.f/(1.f + __expf(-v)));
            }
          } else {
            #pragma unroll
            for (int r=0; r<4; ++r){
              int row = (mi<<4) + rbase + r;
              Ep[row*132 + coln] = f2bf(acc[mi][ni][r]);
            }
          }
        }
    }
    __syncthreads();
    union V16 { u16x4 q[2]; bf16x8 o; };
    if (tt2 == 2){
      // store V^T: dst = 2*TEN + i*32768 + h*8192 + c*256 + j_pix
      // 8 lanes per column -> 128B contiguous aligned segments per instruction
      #pragma unroll
      for (int u=0; u<4; ++u){
        int col = (u<<5) + (t>>3);        // 0..127
        int h2 = col>>5, c2 = col&31;
        int j8 = (t&7)<<3;
        size_t base = 2*(size_t)TEN_ELEMS + ((size_t)(m0>>8))*32768
                    + (size_t)h2*8192 + (size_t)c2*256
                    + (m0&255) + (half<<6) + j8;
        bf16x8 v = *(const bf16x8*)(Ep + col*72 + j8);
        *(bf16x8*)(qkv + base) = v;
      }
    } else if (tt2 < 2){
      int row = (w<<4) + (l>>2);     // 0..63
      int a4  = l&3;
      size_t base = (size_t)tt2*TEN_ELEMS + ((size_t)(m0>>8))*32768
                  + (size_t)((m0&255) + (half<<6) + row)*32;
      #pragma unroll
      for (int u=0; u<4; ++u){
        V16 v;
        v.q[0] = *(const u16x4*)(Ep + row*132 + (u<<5) + (a4<<3));
        v.q[1] = *(const u16x4*)(Ep + row*132 + (u<<5) + (a4<<3) + 4);
        *(bf16x8*)(qkv + base + (size_t)u*8192 + (a4<<3)) = v.o;
      }
    } else {
      int row = (w<<4) + (l>>2);
      int a4  = l&3;
      size_t base = (size_t)(m0 + (half<<6) + row)*128;
      #pragma unroll
      for (int u=0; u<4; ++u){
        V16 v;
        v.q[0] = *(const u16x4*)(Ep + row*132 + (u<<5) + (a4<<3));
        v.q[1] = *(const u16x4*)(Ep + row*132 + (u<<5) + (a4<<3) + 4);
        *(bf16x8*)(gateb + base + (u<<5) + (a4<<3)) = v.o;
      }
    }
  }
}

// ---------------- K3: attention (register-resident, swapped QK^T) ----------------
// K: [i][h][j][c], V^T: [i][h][c][j]. Per block: one (i,h); per wave: 64 j rows.
__global__ __launch_bounds__(256,2) void k_attn(const u16* __restrict__ Qb,
                                                const u16* __restrict__ Kb,
                                                const u16* __restrict__ Vt,
                                                const float* __restrict__ bias_s,
                                                const u16* __restrict__ gateb,
                                                u16* __restrict__ Og){
  __shared__ __align__(16) u16 Pls[4][4224];   // per-wave P[16 j][264 k]
  int t = threadIdx.x, l = t&63, w = t>>6;
  int i = blockIdx.x>>2, h = blockIdx.x&3;
  size_t base2 = ((size_t)(i*4+h))<<13;        // *8192 elements
  int cbase = l&15, g = l>>4;
  // K fragments: kf[f] = K[f*16+cbase][g*8 .. +8]  (coalesced 1KB per load)
  bf16x8 kf[16];
  #pragma unroll
  for (int f=0; f<16; ++f)
    kf[f] = *(const bf16x8*)(Kb + base2 + (size_t)(((f<<4)+cbase)<<5) + (g<<3));
  // V fragments: vf[ks][cf] lane holds V[ks*32+g*8+e][cf*16+cbase] from Vt[c][j]
  bf16x8 vf[8][2];
  #pragma unroll
  for (int ks=0; ks<8; ++ks)
    #pragma unroll
    for (int cf=0; cf<2; ++cf)
      vf[ks][cf] = *(const bf16x8*)(Vt + base2 + (size_t)(((cf<<4)+cbase)<<8) + (ks<<5) + (g<<3));
  u16* myP = &Pls[w][0];
  const float SCALE = 0.17677669529663687f;   // 1/sqrt(32)
  #pragma unroll 1
  for (int sj=0; sj<4; ++sj){
    int jloc = (w<<6) + (sj<<4);
    bf16x8 qf = *(const bf16x8*)(Qb + base2 + (size_t)((jloc+cbase)<<5) + (g<<3));
    fx4 sacc[16];
    #pragma unroll
    for (int f=0; f<16; ++f) sacc[f] = (fx4){0.f,0.f,0.f,0.f};
    // S^T: lane holds S[j=jloc+cbase][katt=f*16+g*4+r]
    #pragma unroll
    for (int f=0; f<16; ++f)
      sacc[f] = __builtin_amdgcn_mfma_f32_16x16x32_bf16(kf[f], qf, sacc[f], 0,0,0);
    // bias_s[h][j][katt]: float4 over r
    const float* bp = bias_s + (((size_t)((h<<8) + jloc + cbase))<<8) + (g<<2);
    #pragma unroll
    for (int f=0; f<16; ++f){
      float4 b4 = *(const float4*)(bp + (f<<4));
      sacc[f][0] = sacc[f][0]*SCALE + b4.x;
      sacc[f][1] = sacc[f][1]*SCALE + b4.y;
      sacc[f][2] = sacc[f][2]*SCALE + b4.z;
      sacc[f][3] = sacc[f][3]*SCALE + b4.w;
    }
    // softmax over katt: 64 in-register + 2 shuffles (g^1, g^2)
    float m = sacc[0][0];
    #pragma unroll
    for (int f=0; f<16; ++f)
      #pragma unroll
      for (int r=0; r<4; ++r) m = fmaxf(m, sacc[f][r]);
    m = fmaxf(m, __shfl_xor(m,16));
    m = fmaxf(m, __shfl_xor(m,32));
    float s = 0.f;
    #pragma unroll
    for (int f=0; f<16; ++f)
      #pragma unroll
      for (int r=0; r<4; ++r){ float p = __expf(sacc[f][r]-m); sacc[f][r] = p; s += p; }
    s += __shfl_xor(s,16);
    s += __shfl_xor(s,32);
    float inv = 1.f/s;
    // P write: 16x ds_write_b64 (4 consecutive katt per write)
    #pragma unroll
    for (int f=0; f<16; ++f){
      u16x4 w4;
      #pragma unroll
      for (int r=0; r<4; ++r) w4[r] = f2bf(sacc[f][r]*inv);
      *(u16x4*)(myP + cbase*264 + (f<<4) + (g<<2)) = w4;
    }
    asm volatile("s_waitcnt lgkmcnt(0)" ::: "memory");
    __builtin_amdgcn_sched_barrier(0);
    fx4 oacc[2] = {};
    #pragma unroll
    for (int ks=0; ks<8; ++ks){
      const bf16x8 pa = *(const bf16x8*)(myP + cbase*264 + (ks<<5) + (g<<3));
      oacc[0] = __builtin_amdgcn_mfma_f32_16x16x32_bf16(pa, vf[ks][0], oacc[0], 0,0,0);
      oacc[1] = __builtin_amdgcn_mfma_f32_16x16x32_bf16(pa, vf[ks][1], oacc[1], 0,0,0);
    }
    #pragma unroll
    for (int cf=0; cf<2; ++cf)
      #pragma unroll
      for (int r=0; r<4; ++r){
        int j = jloc + (g<<2) + r;
        size_t pix = (((size_t)i)<<8) + j;
        int ch = (h<<5) + (cf<<4) + cbase;     // permuted layout [pix][h*32+c]
        float gg = bf2f(gateb[(pix<<7) + ch]);
        Og[(pix<<7) + ch] = f2bf(oacc[cf][r]*gg);
      }
  }
}

// ---------------- K4: output GEMM (prefetch-all, counted vmcnt) ----------------
__global__ __launch_bounds__(256) void k_out(const u16* __restrict__ og,
                                             const u16* __restrict__ wT,
                                             const float* __restrict__ bo,
                                             float* __restrict__ out){
  __shared__ __align__(16) u16 smem[32768];
  int t = threadIdx.x, l = t&63, w = t>>6;
  int m0 = blockIdx.x<<7;
  int wm = w>>1, wn = w&1;
  int rbase = (l>>4)<<2, cbase = l&15, g = l>>4;
  const u16* gA = og + (size_t)m0*128;
  const u16* gB = wT;
  #pragma unroll
  for (int c=0; c<4; ++c)
    stage2(gA + (c<<5), gB + (c<<5), smem + (c<<12), smem + 16384 + (c<<12), t, w);
  fx4 acc[4][4] = {};
  asm volatile("s_waitcnt vmcnt(12)" ::: "memory"); SBAR; SCHEDB;
  mfma16(smem,        smem+16384, acc, wm, wn, cbase, g);
  asm volatile("s_waitcnt vmcnt(8)" ::: "memory");  SBAR; SCHEDB;
  mfma16(smem+4096,   smem+20480, acc, wm, wn, cbase, g);
  asm volatile("s_waitcnt vmcnt(4)" ::: "memory");  SBAR; SCHEDB;
  mfma16(smem+8192,   smem+24576, acc, wm, wn, cbase, g);
  asm volatile("s_waitcnt vmcnt(0)" ::: "memory");  SBAR; SCHEDB;
  mfma16(smem+12288,  smem+28672, acc, wm, wn, cbase, g);
  #pragma unroll
  for (int mi=0; mi<4; ++mi)
    #pragma unroll
    for (int ni=0; ni<4; ++ni){
      int n = (wn<<6)+(ni<<4)+cbase;
      float bn = bo[n];
      #pragma unroll
      for (int r=0; r<4; ++r){
        int m = m0 + (wm<<6)+(mi<<4)+rbase+r;
        out[(((size_t)m)<<7)+n] = acc[mi][ni][r] + bn;
      }
    }
}

extern "C" void kernel_launch(void* const* d_in, const int* in_sizes, int n_in,
                              void* d_out, int out_size, void* d_ws, size_t ws_size,
                              hipStream_t stream) {
  (void)in_sizes; (void)n_in; (void)out_size; (void)ws_size;
  const float* x2d    = (const float*)d_in[0];
  const float* ln_g   = (const float*)d_in[1];
  const float* ln_b   = (const float*)d_in[2];
  const float* W_qkv  = (const float*)d_in[3];
  const float* W_bias = (const float*)d_in[4];
  const float* W_gate = (const float*)d_in[5];
  const float* b_gate = (const float*)d_in[6];
  const float* W_out  = (const float*)d_in[7];
  const float* b_out  = (const float*)d_in[8];
  float* out = (float*)d_out;
  char* ws = (char*)d_ws;
  u16*   lnx    = (u16*)(ws);
  u16*   wcat   = (u16*)(ws + OFF_WCAT);
  u16*   woutT  = (u16*)(ws + OFF_WOUT);
  u16*   qkvb   = (u16*)(ws + OFF_Q);
  float* bias_s = (float*)(ws + OFF_BIAS);
  u16*   gateb  = (u16*)(ws + OFF_GATE);
  u16*   og     = lnx;   // reuse: lnx dead after k_qkv

  hipLaunchKernelGGL(k_prep, dim3(256),      dim3(256), 0, stream, W_qkv, W_gate, W_out, wcat, woutT);
  hipLaunchKernelGGL(k_ln,   dim3(2048),     dim3(256), 0, stream, x2d, ln_g, ln_b, W_bias, lnx, bias_s);
  hipLaunchKernelGGL(k_qkv,  dim3(2048),     dim3(256), 0, stream, lnx, wcat, b_gate, qkvb, gateb);
  hipLaunchKernelGGL(k_attn, dim3(1024),     dim3(256), 0, stream, qkvb, qkvb+TEN_ELEMS, qkvb+2*TEN_ELEMS, bias_s, gateb, og);
  hipLaunchKernelGGL(k_out,  dim3(512),      dim3(256), 0, stream, og, woutT, b_out, out);
}

// Round 7
// 187.434 us; speedup vs baseline: 1.0539x; 1.0539x over previous
//
#include <hip/hip_runtime.h>

#define DEV __device__ __forceinline__

typedef unsigned short u16;
typedef __bf16 bf16x8 __attribute__((ext_vector_type(8)));
typedef u16 u16x4 __attribute__((ext_vector_type(4)));
typedef float fx4 __attribute__((ext_vector_type(4)));

#define NPIX 65536
#define OFF_WCAT  16777216
#define OFF_WOUT  16908288
#define OFF_Q     16941056
#define OFF_BIAS  67272704
#define OFF_GATE  68321280
#define TEN_ELEMS 8388608  // u16 elements per Q/K/V tensor

DEV u16 f2bf(float f){
  unsigned u = __builtin_bit_cast(unsigned, f);
  u += 0x7fffu + ((u>>16)&1u);
  return (u16)(u>>16);
}
DEV float bf2f(u16 s){ return __builtin_bit_cast(float, ((unsigned)s)<<16); }

typedef __attribute__((address_space(1))) unsigned gas_t;
typedef __attribute__((address_space(3))) unsigned las_t;
DEV void gl16(const void* g, void* l){
  __builtin_amdgcn_global_load_lds((gas_t*)g, (las_t*)l, 16, 0, 0);
}

// XOR-ish swizzle for [row][32] bf16 LDS tiles (row stride 64B): chunk' = (cc + row/2) & 3
DEV int swz(int row, int cc){ return row*32 + (((cc + (row>>1))&3)<<3); }

// Stage one 128x32 A-tile + 128x32 B-tile into LDS (4 gl16 per thread).
// Source address pre-swizzled so linear LDS + swizzled read works.
DEV void stage2(const u16* __restrict__ ga, const u16* __restrict__ gb,
                u16* lA, u16* lB, int t, int w){
  #pragma unroll
  for (int s=0; s<2; ++s){
    int idx = (s<<8) + t;
    int row = idx>>2, ccL = idx&3;
    int ccG = (ccL - (row>>1)) & 3;
    gl16(ga + (size_t)row*128 + (ccG<<3), lA + (((s<<2)+w)<<9));
    gl16(gb + (size_t)row*128 + (ccG<<3), lB + (((s<<2)+w)<<9));
  }
}

// One K=32 MFMA step from staged LDS tiles.
DEV void mfma16(const u16* lA, const u16* lB, fx4 (&acc)[4][4],
                int wm, int wn, int cbase, int g){
  bf16x8 a[4], b[4];
  #pragma unroll
  for (int mi=0; mi<4; ++mi)
    a[mi] = *(const bf16x8*)(lA + swz((wm<<6)+(mi<<4)+cbase, g));
  #pragma unroll
  for (int ni=0; ni<4; ++ni)
    b[ni] = *(const bf16x8*)(lB + swz((wn<<6)+(ni<<4)+cbase, g));
  #pragma unroll
  for (int mi=0; mi<4; ++mi)
    #pragma unroll
    for (int ni=0; ni<4; ++ni)
      acc[mi][ni] = __builtin_amdgcn_mfma_f32_16x16x32_bf16(a[mi], b[ni], acc[mi][ni], 0,0,0);
}

// ---------------- K0: weight convert/transpose (column-permuted) ----------------
__global__ __launch_bounds__(256) void k_prep(const float* __restrict__ Wqkv,
                                              const float* __restrict__ Wgate,
                                              const float* __restrict__ Wout,
                                              u16* __restrict__ wcat, u16* __restrict__ woutT){
  int idx = blockIdx.x*256 + threadIdx.x;   // grid = 256 blocks -> idx < 65536
  int np = idx>>7, k = idx&127;
  int tt = np>>7, hh = (np>>5)&3, c = np&31;
  float v;
  if (tt < 3) v = Wqkv[k*384 + c*12 + tt*4 + hh];
  else        v = Wgate[k*128 + c*4 + hh];
  wcat[idx] = f2bf(v);
  if (idx < 16384){
    int n = idx>>7, kp = idx&127;
    int h2 = kp>>5, c2 = kp&31;
    woutT[idx] = f2bf(Wout[(c2*4 + h2)*128 + n]);
  }
}

// ---------------- K1: LN + bias projection ----------------
__global__ __launch_bounds__(256) void k_ln(const float* __restrict__ x,
                                            const float* __restrict__ lng,
                                            const float* __restrict__ lnb,
                                            const float* __restrict__ Wb,
                                            u16* __restrict__ lnx, float* __restrict__ bias_s){
  int lane = threadIdx.x & 63;
  int wid  = (blockIdx.x*256 + threadIdx.x)>>6;
  int nw   = (gridDim.x*256)>>6;
  int c0 = lane<<1;
  float g0 = lng[c0], g1 = lng[c0+1], be0 = lnb[c0], be1 = lnb[c0+1];
  float4 wb0 = *(const float4*)(Wb + (c0<<2));
  float4 wb1 = *(const float4*)(Wb + (c0<<2) + 4);
  for (int p = wid; p < NPIX; p += nw){
    float2 xv = *(const float2*)(x + (((size_t)p)<<7) + c0);
    float s = xv.x + xv.y;
    float s2 = xv.x*xv.x + xv.y*xv.y;
    #pragma unroll
    for (int msk=32; msk>=1; msk>>=1){ s += __shfl_xor(s,msk); s2 += __shfl_xor(s2,msk); }
    float mu = s*(1.f/128.f);
    float var = s2*(1.f/128.f) - mu*mu;
    float rs = rsqrtf(var + 1e-5f);
    float y0 = (xv.x-mu)*rs*g0 + be0;
    float y1 = (xv.y-mu)*rs*g1 + be1;
    unsigned pk = (unsigned)f2bf(y0) | (((unsigned)f2bf(y1))<<16);
    *(unsigned*)(lnx + (((size_t)p)<<7) + c0) = pk;
    float d0 = y0*wb0.x + y1*wb1.x;
    float d1 = y0*wb0.y + y1*wb1.y;
    float d2 = y0*wb0.z + y1*wb1.z;
    float d3 = y0*wb0.w + y1*wb1.w;
    #pragma unroll
    for (int msk=32; msk>=1; msk>>=1){
      d0 += __shfl_xor(d0,msk); d1 += __shfl_xor(d1,msk);
      d2 += __shfl_xor(d2,msk); d3 += __shfl_xor(d3,msk);
    }
    if (lane==0){
      int pi = p>>8, pj = p&255;
      int o = (pj<<8) + pi;          // bias_s[h][j=pj][k=pi]
      bias_s[o] = d0;
      bias_s[65536 + o] = d1;
      bias_s[131072 + o] = d2;
      bias_s[196608 + o] = d3;
    }
  }
}

// ---------------- K2: qkv+gate projection GEMM (R2-style 2-phase, XCD-swizzled) ----------------
// Output layouts: Q,K: [i][h][j][c]; V: [i][h][c][j] (transposed); gate: [pix][h*32+c]
__global__ __launch_bounds__(256,3) void k_qkv(const u16* __restrict__ lnx,
                                               const u16* __restrict__ wcat,
                                               const float* __restrict__ b_gate,
                                               u16* __restrict__ qkv, u16* __restrict__ gateb){
  __shared__ __align__(16) u16 As[4096];
  __shared__ __align__(16) u16 Bs[4096];
  __shared__ __align__(16) u16 Ep[9216];   // [64][132] for Q/K/gate, [128][72] for V^T
  int t = threadIdx.x, l = t&63, w = t>>6;
  int phys = blockIdx.x;
  int virt = ((phys&7)<<8) + (phys>>3);    // XCD-chunked bijection (2048 % 8 == 0)
  int m0 = (virt>>2)<<7;                   // m-major: each XCD owns 64 m-tiles x all n
  int tt2 = virt&3, n0 = tt2<<7;
  int wm = w>>1, wn = w&1;
  int rbase = (l>>4)<<2, cbase = l&15, g = l>>4;
  const u16* gA = lnx  + (size_t)m0*128;
  const u16* gB = wcat + (size_t)n0*128;
  fx4 acc[4][4] = {};
  for (int ks=0; ks<4; ++ks){
    int k0 = ks<<5;
    __syncthreads();
    stage2(gA + k0, gB + k0, As, Bs, t, w);
    asm volatile("s_waitcnt vmcnt(0)" ::: "memory");
    __syncthreads();
    mfma16(As, Bs, acc, wm, wn, cbase, g);
  }
  // Epilogue: restage 128x128 tile through LDS in two 64-row halves.
  for (int half=0; half<2; ++half){
    __syncthreads();
    if (wm == half){
      #pragma unroll
      for (int mi=0; mi<4; ++mi)
        #pragma unroll
        for (int ni=0; ni<4; ++ni){
          int coln = (wn<<6) + (ni<<4) + cbase;
          if (tt2 == 2){
            // V^T restage: EpT[coln][row], pack 4 rows per b64
            u16x4 w4;
            #pragma unroll
            for (int r=0; r<4; ++r) w4[r] = f2bf(acc[mi][ni][r]);
            *(u16x4*)(Ep + coln*72 + (mi<<4) + rbase) = w4;
          } else if (tt2 == 3){
            float bg = b_gate[((coln&31)<<2) + (coln>>5)];
            #pragma unroll
            for (int r=0; r<4; ++r){
              int row = (mi<<4) + rbase + r;
              float v = acc[mi][ni][r] + bg;
              Ep[row*132 + coln] = f2bf(1.f/(1.f + __expf(-v)));
            }
          } else {
            #pragma unroll
            for (int r=0; r<4; ++r){
              int row = (mi<<4) + rbase + r;
              Ep[row*132 + coln] = f2bf(acc[mi][ni][r]);
            }
          }
        }
    }
    __syncthreads();
    union V16 { u16x4 q[2]; bf16x8 o; };
    if (tt2 == 2){
      // store V^T: dst = 2*TEN + i*32768 + h*8192 + c*256 + j_pix
      // 8 lanes per column -> 128B contiguous aligned segments per instruction
      #pragma unroll
      for (int u=0; u<4; ++u){
        int col = (u<<5) + (t>>3);        // 0..127
        int h2 = col>>5, c2 = col&31;
        int j8 = (t&7)<<3;
        size_t base = 2*(size_t)TEN_ELEMS + ((size_t)(m0>>8))*32768
                    + (size_t)h2*8192 + (size_t)c2*256
                    + (m0&255) + (half<<6) + j8;
        bf16x8 v = *(const bf16x8*)(Ep + col*72 + j8);
        *(bf16x8*)(qkv + base) = v;
      }
    } else if (tt2 < 2){
      int row = (w<<4) + (l>>2);     // 0..63
      int a4  = l&3;
      size_t base = (size_t)tt2*TEN_ELEMS + ((size_t)(m0>>8))*32768
                  + (size_t)((m0&255) + (half<<6) + row)*32;
      #pragma unroll
      for (int u=0; u<4; ++u){
        V16 v;
        v.q[0] = *(const u16x4*)(Ep + row*132 + (u<<5) + (a4<<3));
        v.q[1] = *(const u16x4*)(Ep + row*132 + (u<<5) + (a4<<3) + 4);
        *(bf16x8*)(qkv + base + (size_t)u*8192 + (a4<<3)) = v.o;
      }
    } else {
      int row = (w<<4) + (l>>2);
      int a4  = l&3;
      size_t base = (size_t)(m0 + (half<<6) + row)*128;
      #pragma unroll
      for (int u=0; u<4; ++u){
        V16 v;
        v.q[0] = *(const u16x4*)(Ep + row*132 + (u<<5) + (a4<<3));
        v.q[1] = *(const u16x4*)(Ep + row*132 + (u<<5) + (a4<<3) + 4);
        *(bf16x8*)(gateb + base + (u<<5) + (a4<<3)) = v.o;
      }
    }
  }
}

// ---------------- K3: attention (register-resident, swapped QK^T) ----------------
// K: [i][h][j][c], V^T: [i][h][c][j]. Per block: one (i,h); per wave: 64 j rows.
__global__ __launch_bounds__(256,2) void k_attn(const u16* __restrict__ Qb,
                                                const u16* __restrict__ Kb,
                                                const u16* __restrict__ Vt,
                                                const float* __restrict__ bias_s,
                                                const u16* __restrict__ gateb,
                                                u16* __restrict__ Og){
  __shared__ __align__(16) u16 Pls[4][4224];   // per-wave P[16 j][264 k]
  int t = threadIdx.x, l = t&63, w = t>>6;
  int i = blockIdx.x>>2, h = blockIdx.x&3;
  size_t base2 = ((size_t)(i*4+h))<<13;        // *8192 elements
  int cbase = l&15, g = l>>4;
  // K fragments: kf[f] = K[f*16+cbase][g*8 .. +8]  (coalesced 1KB per load)
  bf16x8 kf[16];
  #pragma unroll
  for (int f=0; f<16; ++f)
    kf[f] = *(const bf16x8*)(Kb + base2 + (size_t)(((f<<4)+cbase)<<5) + (g<<3));
  // V fragments: vf[ks][cf] lane holds V[ks*32+g*8+e][cf*16+cbase] from Vt[c][j]
  bf16x8 vf[8][2];
  #pragma unroll
  for (int ks=0; ks<8; ++ks)
    #pragma unroll
    for (int cf=0; cf<2; ++cf)
      vf[ks][cf] = *(const bf16x8*)(Vt + base2 + (size_t)(((cf<<4)+cbase)<<8) + (ks<<5) + (g<<3));
  u16* myP = &Pls[w][0];
  const float SCALE = 0.17677669529663687f;   // 1/sqrt(32)
  #pragma unroll 1
  for (int sj=0; sj<4; ++sj){
    int jloc = (w<<6) + (sj<<4);
    bf16x8 qf = *(const bf16x8*)(Qb + base2 + (size_t)((jloc+cbase)<<5) + (g<<3));
    fx4 sacc[16];
    #pragma unroll
    for (int f=0; f<16; ++f) sacc[f] = (fx4){0.f,0.f,0.f,0.f};
    // S^T: lane holds S[j=jloc+cbase][katt=f*16+g*4+r]
    #pragma unroll
    for (int f=0; f<16; ++f)
      sacc[f] = __builtin_amdgcn_mfma_f32_16x16x32_bf16(kf[f], qf, sacc[f], 0,0,0);
    // bias_s[h][j][katt]: float4 over r
    const float* bp = bias_s + (((size_t)((h<<8) + jloc + cbase))<<8) + (g<<2);
    #pragma unroll
    for (int f=0; f<16; ++f){
      float4 b4 = *(const float4*)(bp + (f<<4));
      sacc[f][0] = sacc[f][0]*SCALE + b4.x;
      sacc[f][1] = sacc[f][1]*SCALE + b4.y;
      sacc[f][2] = sacc[f][2]*SCALE + b4.z;
      sacc[f][3] = sacc[f][3]*SCALE + b4.w;
    }
    // softmax over katt: 64 in-register + 2 shuffles (g^1, g^2)
    float m = sacc[0][0];
    #pragma unroll
    for (int f=0; f<16; ++f)
      #pragma unroll
      for (int r=0; r<4; ++r) m = fmaxf(m, sacc[f][r]);
    m = fmaxf(m, __shfl_xor(m,16));
    m = fmaxf(m, __shfl_xor(m,32));
    float s = 0.f;
    #pragma unroll
    for (int f=0; f<16; ++f)
      #pragma unroll
      for (int r=0; r<4; ++r){ float p = __expf(sacc[f][r]-m); sacc[f][r] = p; s += p; }
    s += __shfl_xor(s,16);
    s += __shfl_xor(s,32);
    float inv = 1.f/s;
    // P write: 16x ds_write_b64 (4 consecutive katt per write)
    #pragma unroll
    for (int f=0; f<16; ++f){
      u16x4 w4;
      #pragma unroll
      for (int r=0; r<4; ++r) w4[r] = f2bf(sacc[f][r]*inv);
      *(u16x4*)(myP + cbase*264 + (f<<4) + (g<<2)) = w4;
    }
    asm volatile("s_waitcnt lgkmcnt(0)" ::: "memory");
    __builtin_amdgcn_sched_barrier(0);
    fx4 oacc[2] = {};
    #pragma unroll
    for (int ks=0; ks<8; ++ks){
      const bf16x8 pa = *(const bf16x8*)(myP + cbase*264 + (ks<<5) + (g<<3));
      oacc[0] = __builtin_amdgcn_mfma_f32_16x16x32_bf16(pa, vf[ks][0], oacc[0], 0,0,0);
      oacc[1] = __builtin_amdgcn_mfma_f32_16x16x32_bf16(pa, vf[ks][1], oacc[1], 0,0,0);
    }
    #pragma unroll
    for (int cf=0; cf<2; ++cf)
      #pragma unroll
      for (int r=0; r<4; ++r){
        int j = jloc + (g<<2) + r;
        size_t pix = (((size_t)i)<<8) + j;
        int ch = (h<<5) + (cf<<4) + cbase;     // permuted layout [pix][h*32+c]
        float gg = bf2f(gateb[(pix<<7) + ch]);
        Og[(pix<<7) + ch] = f2bf(oacc[cf][r]*gg);
      }
  }
}

// ---------------- K4: output GEMM (R2-style 2-phase) ----------------
__global__ __launch_bounds__(256,3) void k_out(const u16* __restrict__ og,
                                               const u16* __restrict__ wT,
                                               const float* __restrict__ bo,
                                               float* __restrict__ out){
  __shared__ __align__(16) u16 As[4096];
  __shared__ __align__(16) u16 Bs[4096];
  int t = threadIdx.x, l = t&63, w = t>>6;
  int m0 = blockIdx.x<<7;
  int wm = w>>1, wn = w&1;
  int rbase = (l>>4)<<2, cbase = l&15, g = l>>4;
  const u16* gA = og + (size_t)m0*128;
  const u16* gB = wT;
  fx4 acc[4][4] = {};
  for (int ks=0; ks<4; ++ks){
    int k0 = ks<<5;
    __syncthreads();
    stage2(gA + k0, gB + k0, As, Bs, t, w);
    asm volatile("s_waitcnt vmcnt(0)" ::: "memory");
    __syncthreads();
    mfma16(As, Bs, acc, wm, wn, cbase, g);
  }
  #pragma unroll
  for (int mi=0; mi<4; ++mi)
    #pragma unroll
    for (int ni=0; ni<4; ++ni){
      int n = (wn<<6)+(ni<<4)+cbase;
      float bn = bo[n];
      #pragma unroll
      for (int r=0; r<4; ++r){
        int m = m0 + (wm<<6)+(mi<<4)+rbase+r;
        out[(((size_t)m)<<7)+n] = acc[mi][ni][r] + bn;
      }
    }
}

extern "C" void kernel_launch(void* const* d_in, const int* in_sizes, int n_in,
                              void* d_out, int out_size, void* d_ws, size_t ws_size,
                              hipStream_t stream) {
  (void)in_sizes; (void)n_in; (void)out_size; (void)ws_size;
  const float* x2d    = (const float*)d_in[0];
  const float* ln_g   = (const float*)d_in[1];
  const float* ln_b   = (const float*)d_in[2];
  const float* W_qkv  = (const float*)d_in[3];
  const float* W_bias = (const float*)d_in[4];
  const float* W_gate = (const float*)d_in[5];
  const float* b_gate = (const float*)d_in[6];
  const float* W_out  = (const float*)d_in[7];
  const float* b_out  = (const float*)d_in[8];
  float* out = (float*)d_out;
  char* ws = (char*)d_ws;
  u16*   lnx    = (u16*)(ws);
  u16*   wcat   = (u16*)(ws + OFF_WCAT);
  u16*   woutT  = (u16*)(ws + OFF_WOUT);
  u16*   qkvb   = (u16*)(ws + OFF_Q);
  float* bias_s = (float*)(ws + OFF_BIAS);
  u16*   gateb  = (u16*)(ws + OFF_GATE);
  u16*   og     = lnx;   // reuse: lnx dead after k_qkv

  hipLaunchKernelGGL(k_prep, dim3(256),      dim3(256), 0, stream, W_qkv, W_gate, W_out, wcat, woutT);
  hipLaunchKernelGGL(k_ln,   dim3(2048),     dim3(256), 0, stream, x2d, ln_g, ln_b, W_bias, lnx, bias_s);
  hipLaunchKernelGGL(k_qkv,  dim3(2048),     dim3(256), 0, stream, lnx, wcat, b_gate, qkvb, gateb);
  hipLaunchKernelGGL(k_attn, dim3(1024),     dim3(256), 0, stream, qkvb, qkvb+TEN_ELEMS, qkvb+2*TEN_ELEMS, bias_s, gateb, og);
  hipLaunchKernelGGL(k_out,  dim3(512),      dim3(256), 0, stream, og, woutT, b_out, out);
}

// Round 10
// 148.332 us; speedup vs baseline: 1.3317x; 1.2636x over previous
//
#include <hip/hip_runtime.h>

#define DEV __device__ __forceinline__

typedef unsigned short u16;
typedef __bf16 bf16x8 __attribute__((ext_vector_type(8)));
typedef u16 u16x4 __attribute__((ext_vector_type(4)));
typedef float fx4 __attribute__((ext_vector_type(4)));

#define NPIX 65536
#define OFF_WCAT  16777216
#define OFF_WOUT  16908288
#define OFF_Q     16941056
#define OFF_BIAS  67272704
#define OFF_GATE  68321280
#define TEN_ELEMS 8388608  // u16 elements per Q/K/V tensor

DEV u16 f2bf(float f){
  unsigned u = __builtin_bit_cast(unsigned, f);
  u += 0x7fffu + ((u>>16)&1u);
  return (u16)(u>>16);
}
DEV float bf2f(u16 s){ return __builtin_bit_cast(float, ((unsigned)s)<<16); }

typedef __attribute__((address_space(1))) unsigned gas_t;
typedef __attribute__((address_space(3))) unsigned las_t;
DEV void gl16(const void* g, void* l){
  __builtin_amdgcn_global_load_lds((gas_t*)g, (las_t*)l, 16, 0, 0);
}

// XOR-ish swizzle for [row][32] bf16 LDS tiles (row stride 64B): chunk' = (cc + row/2) & 3
DEV int swz(int row, int cc){ return row*32 + (((cc + (row>>1))&3)<<3); }

// ---------------- K0: weight convert/transpose (column-permuted) ----------------
// wcat column n' in [0,512): tt = n'>>7 (0=q,1=k,2=v,3=gate), h=(n'>>5)&3, c=n'&31
__global__ __launch_bounds__(256) void k_prep(const float* __restrict__ Wqkv,
                                              const float* __restrict__ Wgate,
                                              const float* __restrict__ Wout,
                                              u16* __restrict__ wcat, u16* __restrict__ woutT){
  int idx = blockIdx.x*256 + threadIdx.x;   // grid = 256 blocks -> idx < 65536
  int np = idx>>7, k = idx&127;
  int tt = np>>7, hh = (np>>5)&3, c = np&31;
  float v;
  if (tt < 3) v = Wqkv[k*384 + c*12 + tt*4 + hh];
  else        v = Wgate[k*128 + c*4 + hh];
  wcat[idx] = f2bf(v);
  if (idx < 16384){
    int n = idx>>7, kp = idx&127;
    int h2 = kp>>5, c2 = kp&31;
    woutT[idx] = f2bf(Wout[(c2*4 + h2)*128 + n]);
  }
}

// ---------------- K1: LN + bias projection ----------------
__global__ __launch_bounds__(256) void k_ln(const float* __restrict__ x,
                                            const float* __restrict__ lng,
                                            const float* __restrict__ lnb,
                                            const float* __restrict__ Wb,
                                            u16* __restrict__ lnx, float* __restrict__ bias_s){
  int lane = threadIdx.x & 63;
  int wid  = (blockIdx.x*256 + threadIdx.x)>>6;
  int nw   = (gridDim.x*256)>>6;
  int c0 = lane<<1;
  float g0 = lng[c0], g1 = lng[c0+1], be0 = lnb[c0], be1 = lnb[c0+1];
  float4 wb0 = *(const float4*)(Wb + (c0<<2));
  float4 wb1 = *(const float4*)(Wb + (c0<<2) + 4);
  for (int p = wid; p < NPIX; p += nw){
    float2 xv = *(const float2*)(x + (((size_t)p)<<7) + c0);
    float s = xv.x + xv.y;
    float s2 = xv.x*xv.x + xv.y*xv.y;
    #pragma unroll
    for (int msk=32; msk>=1; msk>>=1){ s += __shfl_xor(s,msk); s2 += __shfl_xor(s2,msk); }
    float mu = s*(1.f/128.f);
    float var = s2*(1.f/128.f) - mu*mu;
    float rs = rsqrtf(var + 1e-5f);
    float y0 = (xv.x-mu)*rs*g0 + be0;
    float y1 = (xv.y-mu)*rs*g1 + be1;
    unsigned pk = (unsigned)f2bf(y0) | (((unsigned)f2bf(y1))<<16);
    *(unsigned*)(lnx + (((size_t)p)<<7) + c0) = pk;
    float d0 = y0*wb0.x + y1*wb1.x;
    float d1 = y0*wb0.y + y1*wb1.y;
    float d2 = y0*wb0.z + y1*wb1.z;
    float d3 = y0*wb0.w + y1*wb1.w;
    #pragma unroll
    for (int msk=32; msk>=1; msk>>=1){
      d0 += __shfl_xor(d0,msk); d1 += __shfl_xor(d1,msk);
      d2 += __shfl_xor(d2,msk); d3 += __shfl_xor(d3,msk);
    }
    if (lane==0){
      int pi = p>>8, pj = p&255;
      int o = (pj<<8) + pi;          // bias_s[h][j=pj][k=pi]
      bias_s[o] = d0;
      bias_s[65536 + o] = d1;
      bias_s[131072 + o] = d2;
      bias_s[196608 + o] = d3;
    }
  }
}

// ---------------- K2: qkv+gate projection GEMM (exact Round-2 form) ----------------
// Output layouts: Q,K,V: [i][h][j][c]; gate: [pix][h*32+c]
__global__ __launch_bounds__(256,3) void k_qkv(const u16* __restrict__ lnx,
                                               const u16* __restrict__ wcat,
                                               const float* __restrict__ b_gate,
                                               u16* __restrict__ qkv, u16* __restrict__ gateb){
  __shared__ __align__(16) u16 As[4096];
  __shared__ __align__(16) u16 Bs[4096];
  __shared__ __align__(16) u16 Ep[64*132];
  int t = threadIdx.x, l = t&63, w = t>>6;
  int m0 = blockIdx.x<<7, n0 = blockIdx.y<<7;
  int tt2 = n0>>7;
  int wm = w>>1, wn = w&1;
  int rbase = (l>>4)<<2, cbase = l&15;
  fx4 acc[4][4] = {};
  for (int ks=0; ks<4; ++ks){
    int k0 = ks<<5;
    __syncthreads();
    #pragma unroll
    for (int s=0; s<2; ++s){
      int idx = (s<<8) + t;
      int row = idx>>2, ccL = idx&3;
      int ccG = (ccL - (row>>1)) & 3;
      gl16(lnx  + (size_t)(m0+row)*128 + k0 + (ccG<<3), As + (((s<<2)+w)<<9));
      gl16(wcat + (size_t)(n0+row)*128 + k0 + (ccG<<3), Bs + (((s<<2)+w)<<9));
    }
    asm volatile("s_waitcnt vmcnt(0)" ::: "memory");
    __syncthreads();
    bf16x8 a[4], b[4];
    #pragma unroll
    for (int mi=0; mi<4; ++mi)
      a[mi] = *(const bf16x8*)(As + swz((wm<<6)+(mi<<4)+cbase, l>>4));
    #pragma unroll
    for (int ni=0; ni<4; ++ni)
      b[ni] = *(const bf16x8*)(Bs + swz((wn<<6)+(ni<<4)+cbase, l>>4));
    #pragma unroll
    for (int mi=0; mi<4; ++mi)
      #pragma unroll
      for (int ni=0; ni<4; ++ni)
        acc[mi][ni] = __builtin_amdgcn_mfma_f32_16x16x32_bf16(a[mi], b[ni], acc[mi][ni], 0,0,0);
  }
  // Epilogue: restage 128x128 tile through LDS in two 64-row halves, then
  // coalesced 16B stores.
  for (int half=0; half<2; ++half){
    __syncthreads();
    if (wm == half){
      #pragma unroll
      for (int mi=0; mi<4; ++mi)
        #pragma unroll
        for (int ni=0; ni<4; ++ni){
          int coln = (wn<<6) + (ni<<4) + cbase;
          if (tt2 == 3){
            float bg = b_gate[((coln&31)<<2) + (coln>>5)];
            #pragma unroll
            for (int r=0; r<4; ++r){
              int row = (mi<<4) + rbase + r;
              float v = acc[mi][ni][r] + bg;
              Ep[row*132 + coln] = f2bf(1.f/(1.f + __expf(-v)));
            }
          } else {
            #pragma unroll
            for (int r=0; r<4; ++r){
              int row = (mi<<4) + rbase + r;
              Ep[row*132 + coln] = f2bf(acc[mi][ni][r]);
            }
          }
        }
    }
    __syncthreads();
    int row = (w<<4) + (l>>2);     // 0..63
    int a4  = l&3;
    union V16 { u16x4 q[2]; bf16x8 o; };
    if (tt2 < 3){
      // dst = tt*TEN + i*32768 + h*8192 + j*32 + c ; wave writes 1024B contiguous per h
      size_t base = (size_t)tt2*TEN_ELEMS + ((size_t)(m0>>8))*32768
                  + (size_t)((m0&255) + (half<<6) + row)*32;
      #pragma unroll
      for (int u=0; u<4; ++u){
        V16 v;
        v.q[0] = *(const u16x4*)(Ep + row*132 + (u<<5) + (a4<<3));
        v.q[1] = *(const u16x4*)(Ep + row*132 + (u<<5) + (a4<<3) + 4);
        *(bf16x8*)(qkv + base + (size_t)u*8192 + (a4<<3)) = v.o;
      }
    } else {
      size_t base = (size_t)(m0 + (half<<6) + row)*128;
      #pragma unroll
      for (int u=0; u<4; ++u){
        V16 v;
        v.q[0] = *(const u16x4*)(Ep + row*132 + (u<<5) + (a4<<3));
        v.q[1] = *(const u16x4*)(Ep + row*132 + (u<<5) + (a4<<3) + 4);
        *(bf16x8*)(gateb + base + (u<<5) + (a4<<3)) = v.o;
      }
    }
  }
}

// ---------------- K3: attention (swapped QK^T core + Round-2-proven V path) ----------------
// Q,K,V: [i][h][j][c]. Per block: one (i,h); per wave: 64 j rows.
__global__ __launch_bounds__(256,2) void k_attn(const u16* __restrict__ Qb,
                                                const u16* __restrict__ Kb,
                                                const u16* __restrict__ Vb,
                                                const float* __restrict__ bias_s,
                                                const u16* __restrict__ gateb,
                                                u16* __restrict__ Og){
  __shared__ __align__(16) u16 Pls[4][4224];   // per-wave P[16 j][264 k]
  __shared__ __align__(16) u16 Vs[8192];       // V staged [j][c] (Round-2 pattern)
  int t = threadIdx.x, l = t&63, w = t>>6;
  int i = blockIdx.x>>2, h = blockIdx.x&3;
  size_t base2 = ((size_t)(i*4+h))<<13;        // *8192 elements
  int cbase = l&15, g = l>>4;
  // V staging via global_load_lds (Round-2's exact linear pattern)
  #pragma unroll
  for (int s=0; s<4; ++s){
    int idx = (s<<8) + t;
    gl16(Vb + base2 + ((size_t)idx<<3), Vs + (((s<<2)+w)<<9));
  }
  // K fragments: kf[f] = K[f*16+cbase][g*8 .. +8]  (coalesced 1KB per load)
  bf16x8 kf[16];
  #pragma unroll
  for (int f=0; f<16; ++f)
    kf[f] = *(const bf16x8*)(Kb + base2 + (size_t)(((f<<4)+cbase)<<5) + (g<<3));
  asm volatile("s_waitcnt vmcnt(0)" ::: "memory");
  __syncthreads();
  // V fragments from LDS (Round-2's exact per-element build):
  // vf[ks][cf][e] = V[j=ks*32+g*8+e][c=cf*16+cbase]
  bf16x8 vf[8][2];
  #pragma unroll
  for (int ks=0; ks<8; ++ks)
    #pragma unroll
    for (int cf=0; cf<2; ++cf){
      bf16x8 v;
      #pragma unroll
      for (int e=0; e<8; ++e)
        v[e] = __builtin_bit_cast(__bf16, Vs[((ks<<5) + (g<<3) + e)*32 + (cf<<4) + cbase]);
      vf[ks][cf] = v;
    }
  u16* myP = &Pls[w][0];
  const float SCALE = 0.17677669529663687f;   // 1/sqrt(32)
  #pragma unroll 1
  for (int sj=0; sj<4; ++sj){
    int jloc = (w<<6) + (sj<<4);
    bf16x8 qf = *(const bf16x8*)(Qb + base2 + (size_t)((jloc+cbase)<<5) + (g<<3));
    fx4 sacc[16];
    #pragma unroll
    for (int f=0; f<16; ++f) sacc[f] = (fx4){0.f,0.f,0.f,0.f};
    // S^T: lane holds S[j=jloc+cbase][katt=f*16+g*4+r]
    #pragma unroll
    for (int f=0; f<16; ++f)
      sacc[f] = __builtin_amdgcn_mfma_f32_16x16x32_bf16(kf[f], qf, sacc[f], 0,0,0);
    // bias_s[h][j][katt]: float4 over r
    const float* bp = bias_s + (((size_t)((h<<8) + jloc + cbase))<<8) + (g<<2);
    #pragma unroll
    for (int f=0; f<16; ++f){
      float4 b4 = *(const float4*)(bp + (f<<4));
      sacc[f][0] = sacc[f][0]*SCALE + b4.x;
      sacc[f][1] = sacc[f][1]*SCALE + b4.y;
      sacc[f][2] = sacc[f][2]*SCALE + b4.z;
      sacc[f][3] = sacc[f][3]*SCALE + b4.w;
    }
    // softmax over katt: 64 in-register + 2 shuffles (g^1, g^2)
    float m = sacc[0][0];
    #pragma unroll
    for (int f=0; f<16; ++f)
      #pragma unroll
      for (int r=0; r<4; ++r) m = fmaxf(m, sacc[f][r]);
    m = fmaxf(m, __shfl_xor(m,16));
    m = fmaxf(m, __shfl_xor(m,32));
    float s = 0.f;
    #pragma unroll
    for (int f=0; f<16; ++f)
      #pragma unroll
      for (int r=0; r<4; ++r){ float p = __expf(sacc[f][r]-m); sacc[f][r] = p; s += p; }
    s += __shfl_xor(s,16);
    s += __shfl_xor(s,32);
    float inv = 1.f/s;
    // P write: 16x ds_write_b64 (4 consecutive katt per write)
    #pragma unroll
    for (int f=0; f<16; ++f){
      u16x4 w4;
      #pragma unroll
      for (int r=0; r<4; ++r) w4[r] = f2bf(sacc[f][r]*inv);
      *(u16x4*)(myP + cbase*264 + (f<<4) + (g<<2)) = w4;
    }
    asm volatile("s_waitcnt lgkmcnt(0)" ::: "memory");
    __builtin_amdgcn_sched_barrier(0);
    fx4 oacc[2] = {};
    #pragma unroll
    for (int ks=0; ks<8; ++ks){
      const bf16x8 pa = *(const bf16x8*)(myP + cbase*264 + (ks<<5) + (g<<3));
      oacc[0] = __builtin_amdgcn_mfma_f32_16x16x32_bf16(pa, vf[ks][0], oacc[0], 0,0,0);
      oacc[1] = __builtin_amdgcn_mfma_f32_16x16x32_bf16(pa, vf[ks][1], oacc[1], 0,0,0);
    }
    #pragma unroll
    for (int cf=0; cf<2; ++cf)
      #pragma unroll
      for (int r=0; r<4; ++r){
        int j = jloc + (g<<2) + r;
        size_t pix = (((size_t)i)<<8) + j;
        int ch = (h<<5) + (cf<<4) + cbase;     // permuted layout [pix][h*32+c]
        float gg = bf2f(gateb[(pix<<7) + ch]);
        Og[(pix<<7) + ch] = f2bf(oacc[cf][r]*gg);
      }
  }
}

// ---------------- K4: output GEMM (Round-2 form) ----------------
__global__ __launch_bounds__(256,3) void k_out(const u16* __restrict__ og,
                                               const u16* __restrict__ wT,
                                               const float* __restrict__ bo,
                                               float* __restrict__ out){
  __shared__ __align__(16) u16 As[4096];
  __shared__ __align__(16) u16 Bs[4096];
  int t = threadIdx.x, l = t&63, w = t>>6;
  int m0 = blockIdx.x<<7;
  int wm = w>>1, wn = w&1;
  int rbase = (l>>4)<<2, cbase = l&15;
  fx4 acc[4][4] = {};
  for (int ks=0; ks<4; ++ks){
    int k0 = ks<<5;
    __syncthreads();
    #pragma unroll
    for (int s=0; s<2; ++s){
      int idx = (s<<8)+t, row = idx>>2, ccL = idx&3;
      int ccG = (ccL - (row>>1))&3;
      gl16(og + (size_t)(m0+row)*128 + k0 + (ccG<<3), As + (((s<<2)+w)<<9));
      gl16(wT + (size_t)row*128 + k0 + (ccG<<3), Bs + (((s<<2)+w)<<9));
    }
    asm volatile("s_waitcnt vmcnt(0)" ::: "memory");
    __syncthreads();
    bf16x8 a[4], b[4];
    #pragma unroll
    for (int mi=0; mi<4; ++mi)
      a[mi] = *(const bf16x8*)(As + swz((wm<<6)+(mi<<4)+cbase, l>>4));
    #pragma unroll
    for (int ni=0; ni<4; ++ni)
      b[ni] = *(const bf16x8*)(Bs + swz((wn<<6)+(ni<<4)+cbase, l>>4));
    #pragma unroll
    for (int mi=0; mi<4; ++mi)
      #pragma unroll
      for (int ni=0; ni<4; ++ni)
        acc[mi][ni] = __builtin_amdgcn_mfma_f32_16x16x32_bf16(a[mi], b[ni], acc[mi][ni], 0,0,0);
  }
  #pragma unroll
  for (int mi=0; mi<4; ++mi)
    #pragma unroll
    for (int ni=0; ni<4; ++ni){
      int n = (wn<<6)+(ni<<4)+cbase;
      float bn = bo[n];
      #pragma unroll
      for (int r=0; r<4; ++r){
        int m = m0 + (wm<<6)+(mi<<4)+rbase+r;
        out[(((size_t)m)<<7)+n] = acc[mi][ni][r] + bn;
      }
    }
}

extern "C" void kernel_launch(void* const* d_in, const int* in_sizes, int n_in,
                              void* d_out, int out_size, void* d_ws, size_t ws_size,
                              hipStream_t stream) {
  (void)in_sizes; (void)n_in; (void)out_size; (void)ws_size;
  const float* x2d    = (const float*)d_in[0];
  const float* ln_g   = (const float*)d_in[1];
  const float* ln_b   = (const float*)d_in[2];
  const float* W_qkv  = (const float*)d_in[3];
  const float* W_bias = (const float*)d_in[4];
  const float* W_gate = (const float*)d_in[5];
  const float* b_gate = (const float*)d_in[6];
  const float* W_out  = (const float*)d_in[7];
  const float* b_out  = (const float*)d_in[8];
  float* out = (float*)d_out;
  char* ws = (char*)d_ws;
  u16*   lnx    = (u16*)(ws);
  u16*   wcat   = (u16*)(ws + OFF_WCAT);
  u16*   woutT  = (u16*)(ws + OFF_WOUT);
  u16*   qkvb   = (u16*)(ws + OFF_Q);
  float* bias_s = (float*)(ws + OFF_BIAS);
  u16*   gateb  = (u16*)(ws + OFF_GATE);
  u16*   og     = lnx;   // reuse: lnx dead after k_qkv

  hipLaunchKernelGGL(k_prep, dim3(256),      dim3(256), 0, stream, W_qkv, W_gate, W_out, wcat, woutT);
  hipLaunchKernelGGL(k_ln,   dim3(2048),     dim3(256), 0, stream, x2d, ln_g, ln_b, W_bias, lnx, bias_s);
  hipLaunchKernelGGL(k_qkv,  dim3(512,4),    dim3(256), 0, stream, lnx, wcat, b_gate, qkvb, gateb);
  hipLaunchKernelGGL(k_attn, dim3(1024),     dim3(256), 0, stream, qkvb, qkvb+TEN_ELEMS, qkvb+2*TEN_ELEMS, bias_s, gateb, og);
  hipLaunchKernelGGL(k_out,  dim3(512),      dim3(256), 0, stream, og, woutT, b_out, out);
}